// Round 14
// baseline (160.242 us; speedup 1.0000x reference)
//
#include <hip/hip_runtime.h>

// Problem constants (from reference)
#define NS     4096                 // N_SAMPLES
#define NW     64                   // N_WIDTH
#define NNODES 257                  // N_NODES
#define SW     (NS * NW)            // 262144
#define ROW    (NW * NNODES)        // 16448 floats per sample region
#define ROW4   (ROW / 4)            // 4112 float4 groups per sample region
#define SWN    ((size_t)NS * NW * NNODES)  // 67,371,008
#define SPB    4                    // samples per block

// Hard-coded Lagrange basis polynomials over nodes [-1,-0.5,0,0.5,1] (verified R4/R6).
// phi: Horner x^4..x^0; dphi pre-scaled by 128 (1/delta_x); ddphi by 16384.
__device__ __constant__ const float P4[5] = { (float)( 2.0/3.0), (float)(-8.0/3.0),  4.0f, (float)(-8.0/3.0), (float)( 2.0/3.0) };
__device__ __constant__ const float P3[5] = { (float)(-2.0/3.0), (float)( 4.0/3.0),  0.0f, (float)(-4.0/3.0), (float)( 2.0/3.0) };
__device__ __constant__ const float P2[5] = { (float)(-1.0/6.0), (float)( 8.0/3.0), -5.0f, (float)( 8.0/3.0), (float)(-1.0/6.0) };
__device__ __constant__ const float P1[5] = { (float)( 1.0/6.0), (float)(-4.0/3.0),  0.0f, (float)( 4.0/3.0), (float)(-1.0/6.0) };
__device__ __constant__ const float P0[5] = { 0.0f, 0.0f, 1.0f, 0.0f, 0.0f };

__device__ __constant__ const float D3[5] = { (float)( 1024.0/3.0), (float)(-4096.0/3.0),  2048.0f, (float)(-4096.0/3.0), (float)(1024.0/3.0) };
__device__ __constant__ const float D2[5] = { -256.0f, 512.0f, 0.0f, -512.0f, 256.0f };
__device__ __constant__ const float D1[5] = { (float)( -128.0/3.0), (float)( 2048.0/3.0), -1280.0f, (float)( 2048.0/3.0), (float)(-128.0/3.0) };
__device__ __constant__ const float D0[5] = { (float)(   64.0/3.0), (float)( -512.0/3.0),     0.0f, (float)(  512.0/3.0), (float)( -64.0/3.0) };

__device__ __constant__ const float E2[5] = { 131072.0f, -524288.0f, 786432.0f, -524288.0f, 131072.0f };
__device__ __constant__ const float E1[5] = { -65536.0f,  131072.0f,      0.0f, -131072.0f,  65536.0f };
__device__ __constant__ const float E0[5] = { (float)(-16384.0/3.0), (float)(262144.0/3.0), -163840.0f, (float)(262144.0/3.0), (float)(-16384.0/3.0) };

__global__ __launch_bounds__(256) void kann_all(
    const float* __restrict__ x,
    const float* __restrict__ weight,   // [64, 257]
    float* __restrict__ out)
{
    const int tid = threadIdx.x;

    #pragma unroll 1
    for (int s = 0; s < SPB; ++s) {
        const int i = blockIdx.x * SPB + s;     // sample

        // ---- per-sample basis (Horner, no divides; redundant per thread) ----
        const float xs = 256.0f * x[i];
        float fel = floorf(xs * 0.25f);
        fel = fminf(fmaxf(fel, 0.0f), 63.0f);
        const int   b = (int)fel * 4;                    // first affected node (mult of 4)
        const float t = 0.5f * (xs - (float)b) - 1.0f;   // reference coord in [-1,1]

        float bas[3][5];
        #pragma unroll
        for (int j = 0; j < 5; ++j) {
            bas[0][j] = (((P4[j]*t + P3[j])*t + P2[j])*t + P1[j])*t + P0[j];
            bas[1][j] = ((D3[j]*t + D2[j])*t + D1[j])*t + D0[j];
            bas[2][j] = (E2[j]*t + E1[j])*t + E0[j];
        }

        // ---- t/dt/ddt dot products (threads 0..63) ----
        if (tid < NW) {
            const float* wrow = weight + tid * NNODES + b;
            float s0 = 0.0f, s1 = 0.0f, s2 = 0.0f;
            #pragma unroll
            for (int j = 0; j < 5; ++j) {
                const float w = wrow[j];
                s0 += w * bas[0][j];
                s1 += w * bas[1][j];
                s2 += w * bas[2][j];
            }
            out[(size_t)i * NW + tid]                   = s0;
            out[SW + (size_t)i * NW + tid]              = s1;
            out[2 * (size_t)SW + (size_t)i * NW + tid]  = s2;
        }
        if (i == 0 && tid == 64)
            out[3 * (size_t)SW + 3 * SWN] = 0.0078125f;  // delta_x

        // ---- hit precompute (register-resident; <=2 hits per thread) ----
        // Nonzero float4 groups of the 4-row period: om = 64*rho + g0 + p,
        // component c holds bas[a][4p + c - rho] (zero if out of [0,4]).
        // Thread's group o = tid + 256*n has om = (tid - n) mod 257, so the
        // hit iteration for om=gm is n = (tid - gm) mod 257, valid when n <= 16.
        const int g0 = b >> 2;
        int h0 = -1, h1 = -1;
        float w0v[3][4], w1v[3][4];
        #pragma unroll
        for (int a = 0; a < 3; ++a)
            #pragma unroll
            for (int c = 0; c < 4; ++c) { w0v[a][c] = 0.0f; w1v[a][c] = 0.0f; }

        #pragma unroll
        for (int rho = 0; rho < 4; ++rho) {
            #pragma unroll
            for (int p = 0; p < 2; ++p) {
                const int gm = 64 * rho + g0 + p;
                int d = tid - gm;
                if (d < 0) d += 257;
                if (d < 17) {
                    h1 = h0;
                    #pragma unroll
                    for (int a = 0; a < 3; ++a)
                        #pragma unroll
                        for (int c = 0; c < 4; ++c) w1v[a][c] = w0v[a][c];
                    h0 = d;
                    #pragma unroll
                    for (int a = 0; a < 3; ++a) {
                        #pragma unroll
                        for (int c = 0; c < 4; ++c) {
                            const int j = 4 * p + c - rho;          // compile-time
                            w0v[a][c] = (j >= 0 && j <= 4) ? bas[a][j] : 0.0f;
                        }
                    }
                }
            }
        }

        // ---- pure store machine (R6-identical): wave-uniform full-width ----
        float* big = out + 3 * (size_t)SW + (size_t)i * ROW;
        float4* r0 = reinterpret_cast<float4*>(big);
        float4* r1 = reinterpret_cast<float4*>(big + SWN);
        float4* r2 = reinterpret_cast<float4*>(big + 2 * SWN);

        #pragma unroll
        for (int n = 0; n < 16; ++n) {
            const int o = tid + (n << 8);
            float v[3][4];
            #pragma unroll
            for (int a = 0; a < 3; ++a) {
                #pragma unroll
                for (int c = 0; c < 4; ++c) {
                    const float t1 = (n == h1) ? w1v[a][c] : 0.0f;
                    v[a][c]        = (n == h0) ? w0v[a][c] : t1;
                }
            }
            r0[o] = make_float4(v[0][0], v[0][1], v[0][2], v[0][3]);
            r1[o] = make_float4(v[1][0], v[1][1], v[1][2], v[1][3]);
            r2[o] = make_float4(v[2][0], v[2][1], v[2][2], v[2][3]);
        }

        // tail: groups 4096..4111 (16 of them), threads 0..15
        if (tid < 16) {
            const int n = 16;
            const int o = tid + (n << 8);
            float v[3][4];
            #pragma unroll
            for (int a = 0; a < 3; ++a) {
                #pragma unroll
                for (int c = 0; c < 4; ++c) {
                    const float t1 = (n == h1) ? w1v[a][c] : 0.0f;
                    v[a][c]        = (n == h0) ? w0v[a][c] : t1;
                }
            }
            r0[o] = make_float4(v[0][0], v[0][1], v[0][2], v[0][3]);
            r1[o] = make_float4(v[1][0], v[1][1], v[1][2], v[1][3]);
            r2[o] = make_float4(v[2][0], v[2][1], v[2][2], v[2][3]);
        }
    }
}

extern "C" void kernel_launch(void* const* d_in, const int* in_sizes, int n_in,
                              void* d_out, int out_size, void* d_ws, size_t ws_size,
                              hipStream_t stream) {
    const float* x      = (const float*)d_in[0];
    const float* weight = (const float*)d_in[1];
    float* out          = (float*)d_out;
    kann_all<<<NS / SPB, 256, 0, stream>>>(x, weight, out);
}

// Round 15
// 152.715 us; speedup vs baseline: 1.0493x; 1.0493x over previous
//
#include <hip/hip_runtime.h>

// Problem constants (from reference)
#define NS     4096                 // N_SAMPLES
#define NW     64                   // N_WIDTH
#define NNODES 257                  // N_NODES
#define SW     (NS * NW)            // 262144
#define ROW    (NW * NNODES)        // 16448 floats per sample region
#define ROW4   (ROW / 4)            // 4112 float4 groups per sample region
#define SWN    ((size_t)NS * NW * NNODES)  // 67,371,008

// Hard-coded Lagrange basis polynomials over nodes [-1,-0.5,0,0.5,1] (verified R4/R6).
// phi: Horner x^4..x^0; dphi pre-scaled by 128 (1/delta_x); ddphi by 16384.
__device__ __constant__ const float P4[5] = { (float)( 2.0/3.0), (float)(-8.0/3.0),  4.0f, (float)(-8.0/3.0), (float)( 2.0/3.0) };
__device__ __constant__ const float P3[5] = { (float)(-2.0/3.0), (float)( 4.0/3.0),  0.0f, (float)(-4.0/3.0), (float)( 2.0/3.0) };
__device__ __constant__ const float P2[5] = { (float)(-1.0/6.0), (float)( 8.0/3.0), -5.0f, (float)( 8.0/3.0), (float)(-1.0/6.0) };
__device__ __constant__ const float P1[5] = { (float)( 1.0/6.0), (float)(-4.0/3.0),  0.0f, (float)( 4.0/3.0), (float)(-1.0/6.0) };
__device__ __constant__ const float P0[5] = { 0.0f, 0.0f, 1.0f, 0.0f, 0.0f };

__device__ __constant__ const float D3[5] = { (float)( 1024.0/3.0), (float)(-4096.0/3.0),  2048.0f, (float)(-4096.0/3.0), (float)(1024.0/3.0) };
__device__ __constant__ const float D2[5] = { -256.0f, 512.0f, 0.0f, -512.0f, 256.0f };
__device__ __constant__ const float D1[5] = { (float)( -128.0/3.0), (float)( 2048.0/3.0), -1280.0f, (float)( 2048.0/3.0), (float)(-128.0/3.0) };
__device__ __constant__ const float D0[5] = { (float)(   64.0/3.0), (float)( -512.0/3.0),     0.0f, (float)(  512.0/3.0), (float)( -64.0/3.0) };

__device__ __constant__ const float E2[5] = { 131072.0f, -524288.0f, 786432.0f, -524288.0f, 131072.0f };
__device__ __constant__ const float E1[5] = { -65536.0f,  131072.0f,      0.0f, -131072.0f,  65536.0f };
__device__ __constant__ const float E0[5] = { (float)(-16384.0/3.0), (float)(262144.0/3.0), -163840.0f, (float)(262144.0/3.0), (float)(-16384.0/3.0) };

__global__ __launch_bounds__(256) void kann_all(
    const float* __restrict__ x,
    const float* __restrict__ weight,   // [64, 257]
    float* __restrict__ out)
{
    const int i   = blockIdx.x;       // sample
    const int tid = threadIdx.x;

    // ---- per-sample basis (Horner, no divides; redundant per thread) ----
    const float xs = 256.0f * x[i];
    float fel = floorf(xs * 0.25f);
    fel = fminf(fmaxf(fel, 0.0f), 63.0f);
    const int   b = (int)fel * 4;                    // first affected node (mult of 4)
    const float t = 0.5f * (xs - (float)b) - 1.0f;   // reference coord in [-1,1]

    float bas[3][5];
    #pragma unroll
    for (int j = 0; j < 5; ++j) {
        bas[0][j] = (((P4[j]*t + P3[j])*t + P2[j])*t + P1[j])*t + P0[j];
        bas[1][j] = ((D3[j]*t + D2[j])*t + D1[j])*t + D0[j];
        bas[2][j] = (E2[j]*t + E1[j])*t + E0[j];
    }

    // ---- t/dt/ddt dot products (threads 0..63) ----
    if (tid < NW) {
        const float* wrow = weight + tid * NNODES + b;
        float s0 = 0.0f, s1 = 0.0f, s2 = 0.0f;
        #pragma unroll
        for (int j = 0; j < 5; ++j) {
            const float w = wrow[j];
            s0 += w * bas[0][j];
            s1 += w * bas[1][j];
            s2 += w * bas[2][j];
        }
        out[(size_t)i * NW + tid]                   = s0;
        out[SW + (size_t)i * NW + tid]              = s1;
        out[2 * (size_t)SW + (size_t)i * NW + tid]  = s2;
    }
    if (i == 0 && tid == 64)
        out[3 * (size_t)SW + 3 * SWN] = 0.0078125f;  // delta_x

    // ---- hit precompute (register-resident; <=2 hits per thread) ----
    // Nonzero float4 groups of the 4-row period: om = 64*rho + g0 + p,
    // component c holds bas[a][4p + c - rho] (zero if out of [0,4]).
    // Thread's group o = tid + 256*n has om = (tid - n) mod 257, so the hit
    // iteration for om=gm is n = (tid - gm) mod 257, valid when n <= 16.
    const int g0 = b >> 2;
    int h0 = -1, h1 = -1;
    float w0v[3][4], w1v[3][4];
    #pragma unroll
    for (int a = 0; a < 3; ++a)
        #pragma unroll
        for (int c = 0; c < 4; ++c) { w0v[a][c] = 0.0f; w1v[a][c] = 0.0f; }

    #pragma unroll
    for (int rho = 0; rho < 4; ++rho) {
        #pragma unroll
        for (int p = 0; p < 2; ++p) {
            const int gm = 64 * rho + g0 + p;
            int d = tid - gm;
            if (d < 0) d += 257;
            if (d < 17) {
                h1 = h0;
                #pragma unroll
                for (int a = 0; a < 3; ++a)
                    #pragma unroll
                    for (int c = 0; c < 4; ++c) w1v[a][c] = w0v[a][c];
                h0 = d;
                #pragma unroll
                for (int a = 0; a < 3; ++a) {
                    #pragma unroll
                    for (int c = 0; c < 4; ++c) {
                        const int j = 4 * p + c - rho;          // compile-time
                        w0v[a][c] = (j >= 0 && j <= 4) ? bas[a][j] : 0.0f;
                    }
                }
            }
        }
    }

    // ---- pure store machine: wave-uniform full-width stores, no branches ----
    float* big = out + 3 * (size_t)SW + (size_t)i * ROW;
    float4* r0 = reinterpret_cast<float4*>(big);
    float4* r1 = reinterpret_cast<float4*>(big + SWN);
    float4* r2 = reinterpret_cast<float4*>(big + 2 * SWN);

    #pragma unroll
    for (int n = 0; n < 16; ++n) {
        const int o = tid + (n << 8);
        float v[3][4];
        #pragma unroll
        for (int a = 0; a < 3; ++a) {
            #pragma unroll
            for (int c = 0; c < 4; ++c) {
                const float t1 = (n == h1) ? w1v[a][c] : 0.0f;
                v[a][c]        = (n == h0) ? w0v[a][c] : t1;
            }
        }
        r0[o] = make_float4(v[0][0], v[0][1], v[0][2], v[0][3]);
        r1[o] = make_float4(v[1][0], v[1][1], v[1][2], v[1][3]);
        r2[o] = make_float4(v[2][0], v[2][1], v[2][2], v[2][3]);
    }

    // tail: groups 4096..4111 (16 of them), threads 0..15; 256B contiguous
    if (tid < 16) {
        const int n = 16;
        const int o = tid + (n << 8);
        float v[3][4];
        #pragma unroll
        for (int a = 0; a < 3; ++a) {
            #pragma unroll
            for (int c = 0; c < 4; ++c) {
                const float t1 = (n == h1) ? w1v[a][c] : 0.0f;
                v[a][c]        = (n == h0) ? w0v[a][c] : t1;
            }
        }
        r0[o] = make_float4(v[0][0], v[0][1], v[0][2], v[0][3]);
        r1[o] = make_float4(v[1][0], v[1][1], v[1][2], v[1][3]);
        r2[o] = make_float4(v[2][0], v[2][1], v[2][2], v[2][3]);
    }
}

extern "C" void kernel_launch(void* const* d_in, const int* in_sizes, int n_in,
                              void* d_out, int out_size, void* d_ws, size_t ws_size,
                              hipStream_t stream) {
    const float* x      = (const float*)d_in[0];
    const float* weight = (const float*)d_in[1];
    float* out          = (float*)d_out;
    kann_all<<<NS, 256, 0, stream>>>(x, weight, out);
}